// Round 4
// baseline (361.101 us; speedup 1.0000x reference)
//
#include <hip/hip_runtime.h>
#include <hip/hip_bf16.h>
#include <stdint.h>

#define D 1024
#define NSUP 256
#define ROWS 16384   // 4*4096
#define MB 32        // rows per block
#define LTHREADS 512
#define LGRID (ROWS / MB)   // 512 blocks -> 2 blocks/CU

typedef __attribute__((__ext_vector_type__(8))) __bf16 bf16x8;
typedef __attribute__((__ext_vector_type__(4))) float f32x4;
typedef __attribute__((__ext_vector_type__(4))) uint32_t u32x4;

#define MFMA16(a, b, c) __builtin_amdgcn_mfma_f32_16x16x32_bf16((a), (b), (c), 0, 0, 0)

__global__ void cast_k_kernel(const float* __restrict__ K, __bf16* __restrict__ Kb) {
    int i = (blockIdx.x * 256 + threadIdx.x) * 4;
    float4 v = *(const float4*)(K + i);
    __bf16 o[4] __attribute__((aligned(8)));
    o[0] = (__bf16)v.x; o[1] = (__bf16)v.y; o[2] = (__bf16)v.z; o[3] = (__bf16)v.w;
    *(uint2*)(Kb + i) = *(const uint2*)o;
}

// V [4][256][1024] f32 -> Vt [4][1024][256] bf16
__global__ void transpose_v_kernel(const float* __restrict__ V, __bf16* __restrict__ Vt) {
    __shared__ __bf16 tile[64][72];
    int l = blockIdx.z;
    int d0 = blockIdx.x * 64, n0 = blockIdx.y * 64;
    const float* Vl = V + (size_t)l * NSUP * D;
    __bf16* Vtl = Vt + (size_t)l * D * NSUP;
    for (int j = 0; j < 16; ++j) {
        int idx = j * 256 + threadIdx.x;
        int n_l = idx >> 6, d_l = idx & 63;
        tile[d_l][n_l] = (__bf16)Vl[(size_t)(n0 + n_l) * D + d0 + d_l];
    }
    __syncthreads();
    for (int j = 0; j < 16; ++j) {
        int idx = j * 256 + threadIdx.x;
        int d_l = idx >> 6, n_l = idx & 63;
        Vtl[(size_t)(d0 + d_l) * NSUP + n0 + n_l] = tile[d_l][n_l];
    }
}

// One fused CleanUpKV layer, single-shot staging (no intra-phase barriers).
// LDS pool (64KB) holds hn[32][1024] bf16 swizzled during Phase A; after
// Phase A the region is dead and gets reused for w (16KB) and the epilogue
// staging (64KB). Global h is stored LINEAR; the swizzle is applied by
// permuting the global SOURCE on stage and the LDS address on epi readout.
template<bool IN_F32, bool OUT_F32>
__global__ __launch_bounds__(LTHREADS, 4)
void layer_kernel(const void* __restrict__ h_in, void* __restrict__ h_out,
                  const __bf16* __restrict__ Kb, const __bf16* __restrict__ Vt) {
    const int tid = threadIdx.x;
    const int lane = tid & 63;
    const int cg = tid >> 6;            // wave 0..7
    const int llo = lane & 15, lhi = lane >> 4;
    const int sA = (llo & 7) << 4;      // read-side swizzle key
    const int row0 = blockIdx.x * MB;

    __shared__ __align__(16) char pool[65536];
    __shared__ float red1[MB][8];
    __shared__ float red2[MB][8];
    __shared__ float rnin_s[MB];

    // ---------- Staging: full 32x1024 hn tile into pool ----------
    if constexpr (IN_F32) {
        // fused row-norm pre-pass over f32 x
        const float4* x4 = (const float4*)h_in;
        #pragma unroll
        for (int rr = 0; rr < 4; ++rr) {
            int row = cg * 4 + rr;
            const float4* p = x4 + (size_t)(row0 + row) * 256;
            float s = 0.f;
            #pragma unroll
            for (int j = 0; j < 4; ++j) {
                float4 v = p[j * 64 + lane];
                s += v.x * v.x + v.y * v.y + v.z * v.z + v.w * v.w;
            }
            #pragma unroll
            for (int off = 1; off < 64; off <<= 1) s += __shfl_xor(s, off);
            if (lane == 0) rnin_s[row] = 1.f / (sqrtf(s) + 1e-9f);
        }
        __syncthreads();
        int srow = tid >> 4;
        float rn = rnin_s[srow];
        int ss = (srow & 7) << 4;
        const float4* base = (const float4*)((const float*)h_in + (size_t)(row0 + srow) * D) + (tid & 15) * 4;
        #pragma unroll
        for (int q = 0; q < 4; ++q) {
            __bf16 tmp[16] __attribute__((aligned(16)));
            #pragma unroll
            for (int i = 0; i < 4; ++i) {
                float4 v = base[q * 64 + i];
                tmp[4 * i + 0] = (__bf16)(v.x * rn);
                tmp[4 * i + 1] = (__bf16)(v.y * rn);
                tmp[4 * i + 2] = (__bf16)(v.z * rn);
                tmp[4 * i + 3] = (__bf16)(v.w * rn);
            }
            int b = (tid & 15) * 32 + q * 512;
            *(bf16x8*)(pool + srow * 2048 + (b ^ ss))        = *(const bf16x8*)(tmp);
            *(bf16x8*)(pool + srow * 2048 + ((b + 16) ^ ss)) = *(const bf16x8*)(tmp + 8);
        }
    } else {
        // pure copy: bf16 hn, pre-swizzled global source, linear LDS dest
        #pragma unroll
        for (int j = 0; j < 8; ++j) {
            int L = j * 8192 + tid * 16;
            int row = L >> 11;
            int b = L & 2047;
            const char* g = (const char*)h_in + (size_t)(row0 + row) * 2048 + (b ^ ((row & 7) << 4));
            __builtin_amdgcn_global_load_lds(
                (const __attribute__((address_space(1))) uint32_t*)g,
                (__attribute__((address_space(3))) uint32_t*)(pool + L), 16, 0, 0);
        }
    }
    __syncthreads();

    // ---------- Phase A: scores[32x256] = hn @ K^T (one long MFMA stream) ----------
    f32x4 acc[2][2];
    #pragma unroll
    for (int rf = 0; rf < 2; ++rf)
        #pragma unroll
        for (int cf = 0; cf < 2; ++cf)
            acc[rf][cf] = (f32x4){0.f, 0.f, 0.f, 0.f};

    const __bf16* kb0 = Kb + (size_t)(cg * 32 + llo) * D + lhi * 8;
    #pragma unroll 8
    for (int k = 0; k < 32; ++k) {
        bf16x8 a0 = *(const bf16x8*)(pool + llo * 2048 + ((k * 64 + lhi * 16) ^ sA));
        bf16x8 a1 = *(const bf16x8*)(pool + (16 + llo) * 2048 + ((k * 64 + lhi * 16) ^ sA));
        #pragma unroll
        for (int cf = 0; cf < 2; ++cf) {
            bf16x8 b = *(const bf16x8*)(kb0 + cf * 16 * D + k * 32);
            acc[0][cf] = MFMA16(a0, b, acc[0][cf]);
            acc[1][cf] = MFMA16(a1, b, acc[1][cf]);
        }
    }

    // ---------- Phase B: softmax over 256 cols ----------
    float rmax[2][4];
    #pragma unroll
    for (int rf = 0; rf < 2; ++rf)
        #pragma unroll
        for (int r = 0; r < 4; ++r) {
            float m = fmaxf(acc[rf][0][r], acc[rf][1][r]);
            #pragma unroll
            for (int off = 1; off < 16; off <<= 1) m = fmaxf(m, __shfl_xor(m, off));
            rmax[rf][r] = m;
            if (llo == 0) red1[rf * 16 + lhi * 4 + r][cg] = m;
        }
    __syncthreads();
    #pragma unroll
    for (int rf = 0; rf < 2; ++rf)
        #pragma unroll
        for (int r = 0; r < 4; ++r) {
            int row = rf * 16 + lhi * 4 + r;
            f32x4 m0 = *(const f32x4*)&red1[row][0];
            f32x4 m1 = *(const f32x4*)&red1[row][4];
            float m = fmaxf(fmaxf(fmaxf(m0[0], m0[1]), fmaxf(m0[2], m0[3])),
                            fmaxf(fmaxf(m1[0], m1[1]), fmaxf(m1[2], m1[3])));
            float s = 0.f;
            #pragma unroll
            for (int cf = 0; cf < 2; ++cf) {
                float e = exp2f((acc[rf][cf][r] - m) * 1.44269504f);
                acc[rf][cf][r] = e;
                s += e;
            }
            #pragma unroll
            for (int off = 1; off < 16; off <<= 1) s += __shfl_xor(s, off);
            if (llo == 0) red2[row][cg] = s;
        }
    __syncthreads();   // also: all Phase-A hn reads complete -> pool reusable for w
    #pragma unroll
    for (int rf = 0; rf < 2; ++rf)
        #pragma unroll
        for (int r = 0; r < 4; ++r) {
            int row = rf * 16 + lhi * 4 + r;
            f32x4 s0 = *(const f32x4*)&red2[row][0];
            f32x4 s1 = *(const f32x4*)&red2[row][4];
            float s = (s0[0] + s0[1] + s0[2] + s0[3]) + (s1[0] + s1[1] + s1[2] + s1[3]);
            float inv = 1.f / s;
            #pragma unroll
            for (int cf = 0; cf < 2; ++cf) {
                int col = cg * 32 + cf * 16 + llo;
                *(__bf16*)(pool + row * 512 + ((col * 2) ^ ((row & 7) << 4))) =
                    (__bf16)(acc[rf][cf][r] * inv);
            }
        }
    __syncthreads();

    // ---------- Phase C: out[32x1024] = w @ V ----------
    f32x4 acc2[2][8];
    #pragma unroll
    for (int rf = 0; rf < 2; ++rf)
        #pragma unroll
        for (int cf = 0; cf < 8; ++cf)
            acc2[rf][cf] = (f32x4){0.f, 0.f, 0.f, 0.f};

    const __bf16* vt0 = Vt + (size_t)(cg * 128 + llo) * NSUP + lhi * 8;
    #pragma unroll
    for (int k = 0; k < 8; ++k) {
        bf16x8 a0 = *(const bf16x8*)(pool + llo * 512 + ((k * 64 + lhi * 16) ^ sA));
        bf16x8 a1 = *(const bf16x8*)(pool + (16 + llo) * 512 + ((k * 64 + lhi * 16) ^ sA));
        #pragma unroll
        for (int cf = 0; cf < 8; ++cf) {
            bf16x8 b = *(const bf16x8*)(vt0 + (size_t)cf * 16 * NSUP + k * 32);
            acc2[0][cf] = MFMA16(a0, b, acc2[0][cf]);
            acc2[1][cf] = MFMA16(a1, b, acc2[1][cf]);
        }
    }

    // ---------- Epilogue ----------
    if constexpr (OUT_F32) {
        __syncthreads();   // all w reads done -> pool reusable
        const int myhalf = cg >> 2;
        #pragma unroll 1
        for (int hh = 0; hh < 2; ++hh) {
            if (myhalf == hh) {
                #pragma unroll
                for (int rf = 0; rf < 2; ++rf)
                    #pragma unroll
                    for (int cf = 0; cf < 8; ++cf) {
                        int dl = (cg & 3) * 128 + cf * 16 + llo;   // 0..511
                        #pragma unroll
                        for (int r = 0; r < 4; ++r) {
                            int row = rf * 16 + lhi * 4 + r;
                            *(float*)(pool + row * 2048 + ((dl * 4) ^ ((row & 7) << 4))) =
                                acc2[rf][cf][r];
                        }
                    }
            }
            __syncthreads();
            #pragma unroll
            for (int j = 0; j < 8; ++j) {
                int L = j * 8192 + tid * 16;
                int row = L >> 11;
                int b = L & 2047;
                f32x4 v = *(const f32x4*)(pool + row * 2048 + (b ^ ((row & 7) << 4)));
                *(f32x4*)((float*)h_out + (size_t)(row0 + row) * D + hh * 512 + (b >> 2)) = v;
            }
            __syncthreads();
        }
    } else {
        // next-layer row norms, then write NORMALIZED bf16 via single-pass LDS staging
        #pragma unroll
        for (int rf = 0; rf < 2; ++rf)
            #pragma unroll
            for (int r = 0; r < 4; ++r) {
                float s = 0.f;
                #pragma unroll
                for (int cf = 0; cf < 8; ++cf) s += acc2[rf][cf][r] * acc2[rf][cf][r];
                #pragma unroll
                for (int off = 1; off < 16; off <<= 1) s += __shfl_xor(s, off);
                if (llo == 0) red2[rf * 16 + lhi * 4 + r][cg] = s;
            }
        __syncthreads();   // all w reads done -> pool reusable
        float rnv[2][4];
        #pragma unroll
        for (int rf = 0; rf < 2; ++rf)
            #pragma unroll
            for (int r = 0; r < 4; ++r) {
                int row = rf * 16 + lhi * 4 + r;
                f32x4 s0 = *(const f32x4*)&red2[row][0];
                f32x4 s1 = *(const f32x4*)&red2[row][4];
                float ss = (s0[0] + s0[1] + s0[2] + s0[3]) + (s1[0] + s1[1] + s1[2] + s1[3]);
                rnv[rf][r] = 1.f / (sqrtf(ss) + 1e-9f);
            }
        #pragma unroll
        for (int rf = 0; rf < 2; ++rf)
            #pragma unroll
            for (int cf = 0; cf < 8; ++cf) {
                int dcol = cg * 128 + cf * 16 + llo;
                #pragma unroll
                for (int r = 0; r < 4; ++r) {
                    int row = rf * 16 + lhi * 4 + r;
                    *(__bf16*)(pool + row * 2048 + ((dcol * 2) ^ ((row & 7) << 4))) =
                        (__bf16)(acc2[rf][cf][r] * rnv[rf][r]);
                }
            }
        __syncthreads();
        #pragma unroll
        for (int j = 0; j < 8; ++j) {
            int L = j * 8192 + tid * 16;
            int row = L >> 11;
            int b = L & 2047;
            u32x4 v = *(const u32x4*)(pool + row * 2048 + (b ^ ((row & 7) << 4)));
            *(u32x4*)((char*)h_out + (size_t)(row0 + row) * 2048 + b) = v;
        }
    }
}

extern "C" void kernel_launch(void* const* d_in, const int* in_sizes, int n_in,
                              void* d_out, int out_size, void* d_ws, size_t ws_size,
                              hipStream_t stream) {
    const float* x = (const float*)d_in[0];
    const float* keys = (const float*)d_in[1];
    const float* values = (const float*)d_in[2];
    float* out = (float*)d_out;

    char* ws = (char*)d_ws;
    __bf16* h  = (__bf16*)(ws);                 // 16384*1024*2 = 33554432 B (normalized hn, linear)
    __bf16* Kb = (__bf16*)(ws + 33554432);      // 4*256*1024*2 = 2097152 B
    __bf16* Vt = (__bf16*)(ws + 35651584);      // 4*1024*256*2 = 2097152 B

    cast_k_kernel<<<1024, 256, 0, stream>>>(keys, Kb);
    transpose_v_kernel<<<dim3(16, 4, 4), 256, 0, stream>>>(values, Vt);

    const int LS = NSUP * D;
    layer_kernel<true,  false><<<LGRID, LTHREADS, 0, stream>>>(x, h, Kb,          Vt);
    layer_kernel<false, false><<<LGRID, LTHREADS, 0, stream>>>(h, h, Kb + LS,     Vt + LS);
    layer_kernel<false, false><<<LGRID, LTHREADS, 0, stream>>>(h, h, Kb + 2 * LS, Vt + 2 * LS);
    layer_kernel<false, true ><<<LGRID, LTHREADS, 0, stream>>>(h, out, Kb + 3 * LS, Vt + 3 * LS);
}

// Round 5
// 337.643 us; speedup vs baseline: 1.0695x; 1.0695x over previous
//
#include <hip/hip_runtime.h>
#include <hip/hip_bf16.h>
#include <stdint.h>

#define D 1024
#define NSUP 256
#define ROWS 16384      // 4*4096
#define MB 64           // rows per block
#define LTHREADS 1024   // 16 waves
#define LGRID (ROWS / MB)   // 256 blocks = 1/CU
#define LDS_BYTES 163840    // h[64][1024]bf16 (128K) + w[64][256]bf16 (32K)

typedef __attribute__((__ext_vector_type__(8))) __bf16 bf16x8;
typedef __attribute__((__ext_vector_type__(4))) float f32x4;

#define MFMA16(a, b, c) __builtin_amdgcn_mfma_f32_16x16x32_bf16((a), (b), (c), 0, 0, 0)

__global__ void cast_k_kernel(const float* __restrict__ K, __bf16* __restrict__ Kb) {
    int i = (blockIdx.x * 256 + threadIdx.x) * 4;
    float4 v = *(const float4*)(K + i);
    __bf16 o[4] __attribute__((aligned(8)));
    o[0] = (__bf16)v.x; o[1] = (__bf16)v.y; o[2] = (__bf16)v.z; o[3] = (__bf16)v.w;
    *(uint2*)(Kb + i) = *(const uint2*)o;
}

// V [4][256][1024] f32 -> Vt [4][1024][256] bf16
__global__ void transpose_v_kernel(const float* __restrict__ V, __bf16* __restrict__ Vt) {
    __shared__ __bf16 tile[64][72];
    int l = blockIdx.z;
    int d0 = blockIdx.x * 64, n0 = blockIdx.y * 64;
    const float* Vl = V + (size_t)l * NSUP * D;
    __bf16* Vtl = Vt + (size_t)l * D * NSUP;
    for (int j = 0; j < 16; ++j) {
        int idx = j * 256 + threadIdx.x;
        int n_l = idx >> 6, d_l = idx & 63;
        tile[d_l][n_l] = (__bf16)Vl[(size_t)(n0 + n_l) * D + d0 + d_l];
    }
    __syncthreads();
    for (int j = 0; j < 16; ++j) {
        int idx = j * 256 + threadIdx.x;
        int d_l = idx >> 6, n_l = idx & 63;
        Vtl[(size_t)(d0 + d_l) * NSUP + n0 + n_l] = tile[d_l][n_l];
    }
}

// All 4 CleanUpKV layers fused; h never leaves LDS.
// Normalization folded into softmax: softmax(hn.k) == softmax((x.k)*rn[row]),
// so h is stored RAW bf16 in LDS and rn lives in registers (rnv[4][4], the
// same (rf,lhi,r)->row mapping as the score accumulators).
// LDS pool: [0,128K) h rows 64x2048B (XOR-swizzled); [128K,160K) w rows 64x512B.
// red1 aliases pool+0, red2 pool+8192 (h region is dead whenever reds are used).
__global__ __launch_bounds__(LTHREADS, 4)
void fused4_kernel(const float* __restrict__ x, float* __restrict__ out,
                   const __bf16* __restrict__ Kb, const __bf16* __restrict__ Vt) {
    extern __shared__ __align__(16) char pool[];
    const int tid = threadIdx.x;
    const int lane = tid & 63;
    const int wv = tid >> 6;            // wave 0..15
    const int llo = lane & 15, lhi = lane >> 4;
    const int swzk = (llo & 7) << 4;    // read-side swizzle key (row = rf*16+llo)
    const int row0 = blockIdx.x * MB;
    char* wbuf = pool + 131072;

    // ---- stage x -> raw bf16 h in LDS; fused layer-0 row sq-norms ----
    {
        const int srow = tid >> 4;      // 0..63
        const int c16 = tid & 15;
        const float* xr = x + (size_t)(row0 + srow) * D;
        const int sk = (srow & 7) << 4;
        float ss = 0.f;
        #pragma unroll
        for (int q = 0; q < 16; ++q) {
            float4 v = *(const float4*)(xr + (c16 + q * 16) * 4);
            ss += v.x * v.x + v.y * v.y + v.z * v.z + v.w * v.w;
            __bf16 t[4] __attribute__((aligned(8)));
            t[0] = (__bf16)v.x; t[1] = (__bf16)v.y; t[2] = (__bf16)v.z; t[3] = (__bf16)v.w;
            *(uint2*)(pool + srow * 2048 + (((c16 + q * 16) * 8) ^ sk)) = *(const uint2*)t;
        }
        ss += __shfl_xor(ss, 1); ss += __shfl_xor(ss, 2);
        ss += __shfl_xor(ss, 4); ss += __shfl_xor(ss, 8);
        if (c16 == 0) *(float*)(wbuf + srow * 4) = 1.f / (sqrtf(ss) + 1e-9f);
    }
    __syncthreads();

    float rnv[4][4];
    #pragma unroll
    for (int rf = 0; rf < 4; ++rf)
        #pragma unroll
        for (int r = 0; r < 4; ++r)
            rnv[rf][r] = *(const float*)(wbuf + (rf * 16 + lhi * 4 + r) * 4);

    #pragma unroll 1
    for (int l = 0; l < 4; ++l) {
        const __bf16* Kl = Kb + (size_t)l * NSUP * D;
        const __bf16* Vl = Vt + (size_t)l * D * NSUP;

        // ---- Phase A: raw scores[64x256] = h @ K^T; wave owns cols [wv*16,+16) ----
        f32x4 acc[4];
        #pragma unroll
        for (int rf = 0; rf < 4; ++rf) acc[rf] = (f32x4){0.f, 0.f, 0.f, 0.f};
        const __bf16* kb0 = Kl + (size_t)(wv * 16 + llo) * D + lhi * 8;
        #pragma unroll 4
        for (int k = 0; k < 32; ++k) {
            bf16x8 b = *(const bf16x8*)(kb0 + k * 32);
            #pragma unroll
            for (int rf = 0; rf < 4; ++rf) {
                bf16x8 a = *(const bf16x8*)(pool + (rf * 16 + llo) * 2048 + ((k * 64 + lhi * 16) ^ swzk));
                acc[rf] = MFMA16(a, b, acc[rf]);
            }
        }
        __syncthreads();   // A-reads done -> h region free for reds

        // ---- Phase B: softmax with rn folded in ----
        #pragma unroll
        for (int rf = 0; rf < 4; ++rf)
            #pragma unroll
            for (int r = 0; r < 4; ++r) {
                float sr = acc[rf][r] * rnv[rf][r];
                acc[rf][r] = sr;
                float m = sr;
                m = fmaxf(m, __shfl_xor(m, 1)); m = fmaxf(m, __shfl_xor(m, 2));
                m = fmaxf(m, __shfl_xor(m, 4)); m = fmaxf(m, __shfl_xor(m, 8));
                if (llo == 0) *(float*)(pool + (rf * 16 + lhi * 4 + r) * 64 + wv * 4) = m;
            }
        __syncthreads();
        #pragma unroll
        for (int rf = 0; rf < 4; ++rf)
            #pragma unroll
            for (int r = 0; r < 4; ++r) {
                int row = rf * 16 + lhi * 4 + r;
                const f32x4* rp = (const f32x4*)(pool + row * 64);
                f32x4 m0 = rp[0], m1 = rp[1], m2 = rp[2], m3 = rp[3];
                float M = fmaxf(fmaxf(fmaxf(m0[0], m0[1]), fmaxf(m0[2], m0[3])),
                                fmaxf(fmaxf(m1[0], m1[1]), fmaxf(m1[2], m1[3])));
                M = fmaxf(M, fmaxf(fmaxf(fmaxf(m2[0], m2[1]), fmaxf(m2[2], m2[3])),
                                   fmaxf(fmaxf(m3[0], m3[1]), fmaxf(m3[2], m3[3]))));
                float e = exp2f((acc[rf][r] - M) * 1.44269504f);
                acc[rf][r] = e;
                float s = e;
                s += __shfl_xor(s, 1); s += __shfl_xor(s, 2);
                s += __shfl_xor(s, 4); s += __shfl_xor(s, 8);
                if (llo == 0) *(float*)(pool + 8192 + row * 64 + wv * 4) = s;
            }
        __syncthreads();
        #pragma unroll
        for (int rf = 0; rf < 4; ++rf)
            #pragma unroll
            for (int r = 0; r < 4; ++r) {
                int row = rf * 16 + lhi * 4 + r;
                const f32x4* rp = (const f32x4*)(pool + 8192 + row * 64);
                f32x4 s0 = rp[0], s1 = rp[1], s2 = rp[2], s3 = rp[3];
                float S = (s0[0] + s0[1] + s0[2] + s0[3]) + (s1[0] + s1[1] + s1[2] + s1[3])
                        + (s2[0] + s2[1] + s2[2] + s2[3]) + (s3[0] + s3[1] + s3[2] + s3[3]);
                float wval = acc[rf][r] / S;
                *(__bf16*)(wbuf + row * 512 + (((wv * 16 + llo) * 2) ^ ((row & 7) << 4))) = (__bf16)wval;
            }
        __syncthreads();   // w visible

        // ---- Phase C: out[64x1024] = w @ V; wave owns d-cols [wv*64,+64) ----
        f32x4 acc2[4][4];
        #pragma unroll
        for (int rf = 0; rf < 4; ++rf)
            #pragma unroll
            for (int cf = 0; cf < 4; ++cf)
                acc2[rf][cf] = (f32x4){0.f, 0.f, 0.f, 0.f};
        const __bf16* vt0 = Vl + (size_t)(wv * 64 + llo) * NSUP + lhi * 8;
        #pragma unroll 2
        for (int k = 0; k < 8; ++k) {
            bf16x8 a[4];
            #pragma unroll
            for (int rf = 0; rf < 4; ++rf)
                a[rf] = *(const bf16x8*)(wbuf + (rf * 16 + llo) * 512 + ((k * 64 + lhi * 16) ^ swzk));
            #pragma unroll
            for (int cf = 0; cf < 4; ++cf) {
                bf16x8 b = *(const bf16x8*)(vt0 + (size_t)cf * 16 * NSUP + k * 32);
                #pragma unroll
                for (int rf = 0; rf < 4; ++rf)
                    acc2[rf][cf] = MFMA16(a[rf], b, acc2[rf][cf]);
            }
        }

        if (l == 3) {
            // ---- final: direct f32 store (16-lane x 4B = dense 64B runs) ----
            #pragma unroll
            for (int rf = 0; rf < 4; ++rf)
                #pragma unroll
                for (int cf = 0; cf < 4; ++cf)
                    #pragma unroll
                    for (int r = 0; r < 4; ++r) {
                        int row = rf * 16 + lhi * 4 + r;
                        out[(size_t)(row0 + row) * D + wv * 64 + cf * 16 + llo] = acc2[rf][cf][r];
                    }
        } else {
            // ---- next-layer rn from acc2; write raw bf16 h back to LDS ----
            #pragma unroll
            for (int rf = 0; rf < 4; ++rf)
                #pragma unroll
                for (int r = 0; r < 4; ++r) {
                    float s = 0.f;
                    #pragma unroll
                    for (int cf = 0; cf < 4; ++cf) s += acc2[rf][cf][r] * acc2[rf][cf][r];
                    s += __shfl_xor(s, 1); s += __shfl_xor(s, 2);
                    s += __shfl_xor(s, 4); s += __shfl_xor(s, 8);
                    if (llo == 0) *(float*)(pool + (rf * 16 + lhi * 4 + r) * 64 + wv * 4) = s;
                }
            __syncthreads();
            #pragma unroll
            for (int rf = 0; rf < 4; ++rf)
                #pragma unroll
                for (int r = 0; r < 4; ++r) {
                    int row = rf * 16 + lhi * 4 + r;
                    const f32x4* rp = (const f32x4*)(pool + row * 64);
                    f32x4 s0 = rp[0], s1 = rp[1], s2 = rp[2], s3 = rp[3];
                    float ss = (s0[0] + s0[1] + s0[2] + s0[3]) + (s1[0] + s1[1] + s1[2] + s1[3])
                             + (s2[0] + s2[1] + s2[2] + s2[3]) + (s3[0] + s3[1] + s3[2] + s3[3]);
                    rnv[rf][r] = 1.f / (sqrtf(ss) + 1e-9f);
                }
            __syncthreads();   // red1 reads done before h writes clobber
            #pragma unroll
            for (int rf = 0; rf < 4; ++rf)
                #pragma unroll
                for (int cf = 0; cf < 4; ++cf)
                    #pragma unroll
                    for (int r = 0; r < 4; ++r) {
                        int row = rf * 16 + lhi * 4 + r;
                        int col = wv * 64 + cf * 16 + llo;
                        *(__bf16*)(pool + row * 2048 + ((col * 2) ^ ((row & 7) << 4))) =
                            (__bf16)acc2[rf][cf][r];
                    }
            __syncthreads();   // h visible for next layer's Phase A
        }
    }
}

extern "C" void kernel_launch(void* const* d_in, const int* in_sizes, int n_in,
                              void* d_out, int out_size, void* d_ws, size_t ws_size,
                              hipStream_t stream) {
    const float* x = (const float*)d_in[0];
    const float* keys = (const float*)d_in[1];
    const float* values = (const float*)d_in[2];
    float* out = (float*)d_out;

    char* ws = (char*)d_ws;
    __bf16* Kb = (__bf16*)(ws);             // 4*256*1024*2 = 2 MB
    __bf16* Vt = (__bf16*)(ws + 2097152);   // 4*1024*256*2 = 2 MB

    (void)hipFuncSetAttribute((const void*)fused4_kernel,
                              hipFuncAttributeMaxDynamicSharedMemorySize, LDS_BYTES);

    cast_k_kernel<<<1024, 256, 0, stream>>>(keys, Kb);
    transpose_v_kernel<<<dim3(16, 4, 4), 256, 0, stream>>>(values, Vt);
    fused4_kernel<<<LGRID, LTHREADS, LDS_BYTES, stream>>>(x, out, Kb, Vt);
}